// Round 1
// baseline (838.313 us; speedup 1.0000x reference)
//
#include <hip/hip_runtime.h>
#include <hip/hip_bf16.h>
#include <math.h>

// Masked dot-product attention, fp32, flash-style online softmax.
// B=32, LQ=LK=2048, D=64. valid_lens[b] masks keys >= vl with -1e6 in the
// reference -> exactly zero softmax weight in fp32 -> we truncate the K loop.

#define B_    32
#define LQ_   2048
#define LK_   2048
#define D_    64
#define QTILE 64
#define KTILE 64

__global__ __launch_bounds__(256) void fa_fp32_kernel(
    const float* __restrict__ Q, const float* __restrict__ K,
    const float* __restrict__ V, const int* __restrict__ vlen,
    float* __restrict__ O)
{
    __shared__ float Kl[KTILE * D_];
    __shared__ float Vl[KTILE * D_];

    const int tid    = threadIdx.x;
    const int qlocal = tid >> 2;   // 0..63: q row within tile
    const int dslice = tid & 3;    // 0..3: which 16-dim slice
    const int b      = blockIdx.y;
    const int qrow   = blockIdx.x * QTILE + qlocal;

    const int vl     = vlen[b];                       // in [1, LK]
    const int ntiles = (vl + KTILE - 1) / KTILE;

    // ---- load my 16-dim slice of the q row (coalesced float4) ----
    const size_t bq = ((size_t)b * LQ_ + qrow) * D_ + dslice * 16;
    float q[16];
#pragma unroll
    for (int c = 0; c < 4; ++c) {
        float4 t = *(const float4*)(Q + bq + c * 4);
        q[c*4+0] = t.x; q[c*4+1] = t.y; q[c*4+2] = t.z; q[c*4+3] = t.w;
    }

    float m = -INFINITY;
    float l = 0.f;
    float o[16];
#pragma unroll
    for (int i = 0; i < 16; ++i) o[i] = 0.f;

    const float scale = 0.125f;  // 1/sqrt(64)

    for (int t = 0; t < ntiles; ++t) {
        const int k0 = t * KTILE;
        __syncthreads();
        {
            // Stage contiguous 16 KiB K-tile and V-tile as float4 (coalesced).
            const float4* kg = (const float4*)(K + ((size_t)b * LK_ + k0) * D_);
            const float4* vg = (const float4*)(V + ((size_t)b * LK_ + k0) * D_);
            float4* ks = (float4*)Kl;
            float4* vs = (float4*)Vl;
#pragma unroll
            for (int i = 0; i < (KTILE * D_ / 4) / 256; ++i) {
                ks[tid + i * 256] = kg[tid + i * 256];
                vs[tid + i * 256] = vg[tid + i * 256];
            }
        }
        __syncthreads();

        const int kmax = vl - k0;  // keys with kk < kmax are valid in this tile

        for (int kk = 0; kk < KTILE; ++kk) {
            // ---- partial dot over my 16 dims, reduce across 4-lane group ----
            float partial = 0.f;
            const float* kr = Kl + kk * D_ + dslice * 16;
#pragma unroll
            for (int i = 0; i < 16; ++i) partial += q[i] * kr[i];
            partial += __shfl_xor(partial, 1);
            partial += __shfl_xor(partial, 2);
            float s = partial * scale;

            if (kk >= kmax) s = -1e30f;  // masked tail -> weight exactly 0

            // ---- online softmax update ----
            const float m_new = fmaxf(m, s);
            const float p     = __expf(s - m_new);
            const float corr  = __expf(m - m_new);  // exp(-inf)=0 on first key
            l = l * corr + p;
            const float* vr = Vl + kk * D_ + dslice * 16;
#pragma unroll
            for (int i = 0; i < 16; ++i) o[i] = o[i] * corr + p * vr[i];
            m = m_new;
        }
    }

    const float inv_l = 1.f / l;
    float* op = O + bq;
#pragma unroll
    for (int c = 0; c < 4; ++c) {
        float4 t;
        t.x = o[c*4+0] * inv_l; t.y = o[c*4+1] * inv_l;
        t.z = o[c*4+2] * inv_l; t.w = o[c*4+3] * inv_l;
        *(float4*)(op + c * 4) = t;
    }
}

extern "C" void kernel_launch(void* const* d_in, const int* in_sizes, int n_in,
                              void* d_out, int out_size, void* d_ws, size_t ws_size,
                              hipStream_t stream) {
    const float* Q    = (const float*)d_in[0];
    const float* K    = (const float*)d_in[1];
    const float* V    = (const float*)d_in[2];
    const int*   vlen = (const int*)d_in[3];
    float*       O    = (float*)d_out;

    dim3 grid(LQ_ / QTILE, B_);
    dim3 block(256);
    fa_fp32_kernel<<<grid, block, 0, stream>>>(Q, K, V, vlen, O);
}

// Round 2
// 187.151 us; speedup vs baseline: 4.4793x; 4.4793x over previous
//
#include <hip/hip_runtime.h>
#include <math.h>

// Masked dot-product attention via bf16 MFMA flash kernel.
// B=32, LQ=LK=2048, D=64, fp32 in/out, per-batch valid_lens.
// Orientation: S^T = K*Q^T and O^T = V^T*P^T so that softmax reductions are
// in-lane + 2 shuffles and P's C-layout converts to B-layout via a per-wave
// swizzled LDS round trip.

#define B_    32
#define LQ_   2048
#define LK_   2048
#define D_    64

typedef __attribute__((ext_vector_type(8))) short  bf16x8;
typedef __attribute__((ext_vector_type(4))) short  s16x4;
typedef __attribute__((ext_vector_type(4))) float  f32x4;

static __device__ __forceinline__ short f2bf(float f) {
    // round-to-nearest-even fp32 -> bf16
    unsigned u = __float_as_uint(f);
    u += 0x7fffu + ((u >> 16) & 1u);
    return (short)(u >> 16);
}

__global__ __launch_bounds__(256) void fa_mfma_kernel(
    const float* __restrict__ Q, const float* __restrict__ K,
    const float* __restrict__ V, const int* __restrict__ vlen,
    float* __restrict__ O)
{
    // LDS: K-tile [key][dim] bf16, V-tile transposed [dim][key] bf16,
    // per-wave P [q][key] bf16. All rows 64 bf16; 16B chunks XOR-swizzled
    // by (row&7) so MFMA b128 fragment reads are bank-balanced.
    __shared__ __align__(16) short Kl[64 * 64];
    __shared__ __align__(16) short Vt[64 * 64];
    __shared__ __align__(16) short Pl[4 * 32 * 64];

    const int tid  = threadIdx.x;
    const int wave = tid >> 6;
    const int lane = tid & 63;
    const int quad = lane >> 4;
    const int c    = lane & 15;

    const int b  = blockIdx.y;
    const int q0 = blockIdx.x * 128 + wave * 32;   // 32 q-rows per wave
    const int vl = vlen[b];
    const int ntiles = (vl + 63) >> 6;

    // fold 1/sqrt(64) and log2(e) into Q so softmax uses exp2
    const float qscale = 0.125f * 1.44269504088896340736f;

    // ---- Q fragments in registers for the whole K loop ----
    // A/B-frag layout: element j of (qf,ds) = Q[q0+qf*16+c][ds*32+quad*8+j]
    bf16x8 qfrag[2][2];
#pragma unroll
    for (int qf = 0; qf < 2; ++qf)
#pragma unroll
        for (int ds = 0; ds < 2; ++ds) {
            const float* qp = Q + ((size_t)(b * LQ_ + q0 + qf * 16 + c)) * D_ + ds * 32 + quad * 8;
            f32x4 t0 = *(const f32x4*)qp;
            f32x4 t1 = *(const f32x4*)(qp + 4);
            bf16x8 fr;
#pragma unroll
            for (int j = 0; j < 4; ++j) {
                fr[j]     = f2bf(t0[j] * qscale);
                fr[j + 4] = f2bf(t1[j] * qscale);
            }
            qfrag[qf][ds] = fr;
        }

    f32x4 oacc[4][2];   // O^T accumulator: [dimtile][qfrag], C-layout
#pragma unroll
    for (int dt = 0; dt < 4; ++dt)
#pragma unroll
        for (int qf = 0; qf < 2; ++qf)
            oacc[dt][qf] = (f32x4){0.f, 0.f, 0.f, 0.f};
    float mrun[2] = {-INFINITY, -INFINITY};
    float lrun[2] = {0.f, 0.f};

    // staging thread mappings
    const int kkey = tid >> 2, kdsl = tid & 3;   // K: 1 key x 16 dims
    const int vkb  = tid & 15, vdb  = tid >> 4;  // V: 4 keys x 4 dims block
    short* myP = Pl + wave * (32 * 64);

    for (int t = 0; t < ntiles; ++t) {
        const int k0 = t * 64;
        __syncthreads();

        // ---- stage K tile: fp32 -> bf16, row-major [key][dim], swizzled ----
        {
            const float* kg = K + ((size_t)(b * LK_ + k0 + kkey)) * D_ + kdsl * 16;
            f32x4 a[4];
#pragma unroll
            for (int i = 0; i < 4; ++i) a[i] = *(const f32x4*)(kg + 4 * i);
#pragma unroll
            for (int h = 0; h < 2; ++h) {
                bf16x8 w;
#pragma unroll
                for (int j = 0; j < 8; ++j) w[j] = f2bf(a[h * 2 + (j >> 2)][j & 3]);
                const int chunkp = (kdsl * 2 + h) ^ (kkey & 7);
                *(bf16x8*)&Kl[kkey * 64 + chunkp * 8] = w;
            }
        }
        // ---- stage V tile transposed: Vt[dim][key], swizzled ----
        {
            const float* vg = V + ((size_t)(b * LK_ + k0 + vkb * 4)) * D_ + vdb * 4;
            f32x4 r[4];
#pragma unroll
            for (int i = 0; i < 4; ++i) r[i] = *(const f32x4*)(vg + 64 * i);
#pragma unroll
            for (int dr = 0; dr < 4; ++dr) {
                const int dim = vdb * 4 + dr;
                s16x4 w = { f2bf(r[0][dr]), f2bf(r[1][dr]), f2bf(r[2][dr]), f2bf(r[3][dr]) };
                const int chunkp = (vkb >> 1) ^ (dim & 7);
                *(s16x4*)&Vt[dim * 64 + chunkp * 8 + (vkb & 1) * 4] = w;
            }
        }
        __syncthreads();

        // ---- S^T = K * Q^T : C-layout row=key(quad*4+reg), col=q(lane&15) ----
        f32x4 st[4][2];
#pragma unroll
        for (int kt = 0; kt < 4; ++kt) {
            bf16x8 kfr[2];
#pragma unroll
            for (int ds = 0; ds < 2; ++ds) {
                const int chunkp = (quad + 4 * ds) ^ (c & 7);
                kfr[ds] = *(const bf16x8*)&Kl[(kt * 16 + c) * 64 + chunkp * 8];
            }
#pragma unroll
            for (int qf = 0; qf < 2; ++qf) {
                f32x4 acc = (f32x4){0.f, 0.f, 0.f, 0.f};
                acc = __builtin_amdgcn_mfma_f32_16x16x32_bf16(kfr[0], qfrag[qf][0], acc, 0, 0, 0);
                acc = __builtin_amdgcn_mfma_f32_16x16x32_bf16(kfr[1], qfrag[qf][1], acc, 0, 0, 0);
                st[kt][qf] = acc;
            }
        }

        // ---- mask tail keys (>= vl) to -1e30 -> weight exactly 0 ----
        if (k0 + 64 > vl) {
#pragma unroll
            for (int kt = 0; kt < 4; ++kt)
#pragma unroll
                for (int reg = 0; reg < 4; ++reg) {
                    const int key = k0 + kt * 16 + quad * 4 + reg;
                    if (key >= vl) {
                        st[kt][0][reg] = -1e30f;
                        st[kt][1][reg] = -1e30f;
                    }
                }
        }

        // ---- online softmax (log2 domain); per-q state lives at col=lane&15 ----
#pragma unroll
        for (int qf = 0; qf < 2; ++qf) {
            float tm = st[0][qf][0];
#pragma unroll
            for (int kt = 0; kt < 4; ++kt)
#pragma unroll
                for (int reg = 0; reg < 4; ++reg) tm = fmaxf(tm, st[kt][qf][reg]);
            tm = fmaxf(tm, __shfl_xor(tm, 16));
            tm = fmaxf(tm, __shfl_xor(tm, 32));
            const float mnew = fmaxf(mrun[qf], tm);
            const float corr = exp2f(mrun[qf] - mnew);   // exp2(-inf)=0 first tile
            mrun[qf] = mnew;
            float rs = 0.f;
#pragma unroll
            for (int kt = 0; kt < 4; ++kt)
#pragma unroll
                for (int reg = 0; reg < 4; ++reg) {
                    const float p = exp2f(st[kt][qf][reg] - mnew);
                    st[kt][qf][reg] = p;
                    rs += p;
                }
            rs += __shfl_xor(rs, 16);
            rs += __shfl_xor(rs, 32);
            lrun[qf] = lrun[qf] * corr + rs;
#pragma unroll
            for (int dt = 0; dt < 4; ++dt) oacc[dt][qf] *= corr;
        }

        // ---- write P to per-wave LDS [q][key] bf16 (packed pairs), swizzled ----
#pragma unroll
        for (int qf = 0; qf < 2; ++qf)
#pragma unroll
            for (int kt = 0; kt < 4; ++kt)
#pragma unroll
                for (int r = 0; r < 2; ++r) {
                    const unsigned lo = (unsigned short)f2bf(st[kt][qf][2 * r]);
                    const unsigned hi = (unsigned short)f2bf(st[kt][qf][2 * r + 1]);
                    const unsigned pk = lo | (hi << 16);
                    const int chunkp = (kt * 2 + (quad >> 1)) ^ (c & 7);
                    const int addr = (qf * 16 + c) * 64 + chunkp * 8 + (quad & 1) * 4 + 2 * r;
                    *(unsigned*)&myP[addr] = pk;
                }

        // ---- O^T += V^T * P^T ----
#pragma unroll
        for (int s = 0; s < 2; ++s) {
            bf16x8 pfr[2];
#pragma unroll
            for (int qf = 0; qf < 2; ++qf) {
                const int chunkp = (s * 4 + quad) ^ (c & 7);
                pfr[qf] = *(const bf16x8*)&myP[(qf * 16 + c) * 64 + chunkp * 8];
            }
#pragma unroll
            for (int dt = 0; dt < 4; ++dt) {
                const int chunkp = (s * 4 + quad) ^ (c & 7);
                bf16x8 vfr = *(const bf16x8*)&Vt[(dt * 16 + c) * 64 + chunkp * 8];
#pragma unroll
                for (int qf = 0; qf < 2; ++qf)
                    oacc[dt][qf] = __builtin_amdgcn_mfma_f32_16x16x32_bf16(vfr, pfr[qf], oacc[dt][qf], 0, 0, 0);
            }
        }
    }

    // ---- epilogue: normalize, store O[q][dim] as float4 ----
#pragma unroll
    for (int qf = 0; qf < 2; ++qf) {
        const float inv = 1.f / lrun[qf];
#pragma unroll
        for (int dt = 0; dt < 4; ++dt) {
            f32x4 v = oacc[dt][qf] * inv;
            float* op = O + ((size_t)(b * LQ_ + q0 + qf * 16 + c)) * D_ + dt * 16 + quad * 4;
            *(f32x4*)op = v;
        }
    }
}

extern "C" void kernel_launch(void* const* d_in, const int* in_sizes, int n_in,
                              void* d_out, int out_size, void* d_ws, size_t ws_size,
                              hipStream_t stream) {
    const float* Q    = (const float*)d_in[0];
    const float* K    = (const float*)d_in[1];
    const float* V    = (const float*)d_in[2];
    const int*   vlen = (const int*)d_in[3];
    float*       O    = (float*)d_out;

    dim3 grid(LQ_ / 128, B_);
    dim3 block(256);
    fa_mfma_kernel<<<grid, block, 0, stream>>>(Q, K, V, vlen, O);
}

// Round 3
// 172.064 us; speedup vs baseline: 4.8721x; 1.0877x over previous
//
#include <hip/hip_runtime.h>
#include <hip/hip_bf16.h>
#include <math.h>

// Masked dot-product attention, bf16 MFMA flash kernel, round 3.
// B=32, LQ=LK=2048, D=64. S^T = K*Q^T and O^T = V^T*P^T with 32x32x16 MFMA.
// 2-wave blocks (64 q rows), double-buffered LDS K/V tiles with register
// prefetch (pipelined across the barrier), shuffle-based P^T B-frags (no P
// LDS round trip), XOR-swizzled LDS (conflict-free b128 reads/writes).

#define B_    32
#define LQ_   2048
#define LK_   2048
#define D_    64

typedef __attribute__((ext_vector_type(8)))  short bf16x8;
typedef __attribute__((ext_vector_type(4)))  float f32x4;
typedef __attribute__((ext_vector_type(16))) float f32x16;

static __device__ __forceinline__ unsigned pk_bf16(float a, float b) {
    __hip_bfloat162 h = __float22bfloat162_rn(float2{a, b});
    return *(unsigned*)&h;   // x in low 16 bits, y in high
}

__global__ __launch_bounds__(128, 2) void fa_mfma3_kernel(
    const float* __restrict__ Q, const float* __restrict__ K,
    const float* __restrict__ V, const int* __restrict__ vlen,
    float* __restrict__ O)
{
    // K tile [key][dim], V tile transposed [dim][key], both bf16 64x64,
    // double buffered. 16B chunks swizzled: pos = chunk ^ (row & 7).
    __shared__ __align__(16) short Kl[2][64 * 64];
    __shared__ __align__(16) short Vt[2][64 * 64];

    const int tid  = threadIdx.x;          // 0..127
    const int wave = tid >> 6;
    const int lane = tid & 63;
    const int c31  = lane & 31;
    const int h    = lane >> 5;

    const int b  = blockIdx.y;
    const int q0 = blockIdx.x * 64 + wave * 32;
    const int vl = vlen[b];
    const int nt = (vl + 63) >> 6;

    const float qscale = 0.125f * 1.44269504088896340736f;  // 1/sqrt(64)*log2(e)

    // ---- Q B-frags in registers: B[k=dim][n=q], dim = ks*16 + h*8 + j ----
    unsigned qfrag[4][4];
#pragma unroll
    for (int ks = 0; ks < 4; ++ks) {
        const float* qp = Q + ((size_t)(b * LQ_ + q0 + c31)) * D_ + ks * 16 + h * 8;
        f32x4 t0 = *(const f32x4*)qp;
        f32x4 t1 = *(const f32x4*)(qp + 4);
#pragma unroll
        for (int jj = 0; jj < 2; ++jj) {
            qfrag[ks][jj]     = pk_bf16(t0[2*jj] * qscale, t0[2*jj+1] * qscale);
            qfrag[ks][jj + 2] = pk_bf16(t1[2*jj] * qscale, t1[2*jj+1] * qscale);
        }
    }

    f32x16 oacc[2];     // O^T acc: dim row = dt*32 + (r&3)+8*(r>>2)+4h, col q = c31
#pragma unroll
    for (int dt = 0; dt < 2; ++dt)
#pragma unroll
        for (int r = 0; r < 16; ++r) oacc[dt][r] = 0.f;
    float mrun = -INFINITY, lrun = 0.f;

    // staging maps
    const int skey = tid >> 1, skh = tid & 1;          // K: half-row each
    const int vkg = tid >> 4, vdg = tid & 15;          // V: 8 keys x 4 dims

    const float* kgp = K + ((size_t)(b * LK_ + skey)) * D_ + skh * 32;
    const float* vgp = V + ((size_t)(b * LK_ + vkg * 8)) * D_ + vdg * 4;

    f32x4 kr[8], vr[8];
    // ---- prologue: prefetch tile 0 into registers ----
#pragma unroll
    for (int i = 0; i < 8; ++i) kr[i] = *(const f32x4*)(kgp + 4 * i);
#pragma unroll
    for (int i = 0; i < 8; ++i) vr[i] = *(const f32x4*)(vgp + (size_t)i * D_);

    for (int t = 0; t < nt; ++t) {
        const int k0 = t * 64;
        const int buf = t & 1;

        // ---- cvt + write tile t to LDS (waits on this tile's loads only) ----
        {
            unsigned pk32[16];
#pragma unroll
            for (int m = 0; m < 16; ++m)
                pk32[m] = pk_bf16(kr[m >> 1][2 * (m & 1)], kr[m >> 1][2 * (m & 1) + 1]);
#pragma unroll
            for (int cch = 0; cch < 4; ++cch) {
                const int pos = (skh * 4 + cch) ^ (skey & 7);
                *(bf16x8*)&Kl[buf][skey * 64 + pos * 8] = *(bf16x8*)&pk32[4 * cch];
            }
#pragma unroll
            for (int dr = 0; dr < 4; ++dr) {
                unsigned w[4];
#pragma unroll
                for (int p = 0; p < 4; ++p)
                    w[p] = pk_bf16(vr[2 * p][dr], vr[2 * p + 1][dr]);
                const int dim = vdg * 4 + dr;
                const int pos = vkg ^ (dim & 7);
                *(bf16x8*)&Vt[buf][dim * 64 + pos * 8] = *(bf16x8*)&w[0];
            }
        }
        // ---- issue prefetch for tile t+1 (stays in flight across barrier) ----
        if (t + 1 < nt) {
            const float* kn = kgp + (size_t)(k0 + 64) * D_;
            const float* vn = vgp + (size_t)(k0 + 64) * D_;
#pragma unroll
            for (int i = 0; i < 8; ++i) kr[i] = *(const f32x4*)(kn + 4 * i);
#pragma unroll
            for (int i = 0; i < 8; ++i) vr[i] = *(const f32x4*)(vn + (size_t)i * D_);
        }
        __syncthreads();

        // ---- S^T = K * Q^T : 2 key-tiles x 4 k-steps of 32x32x16 ----
        f32x16 st[2];
#pragma unroll
        for (int s = 0; s < 2; ++s) {
#pragma unroll
            for (int r = 0; r < 16; ++r) st[s][r] = 0.f;
#pragma unroll
            for (int ks = 0; ks < 4; ++ks) {
                const int pos = (ks * 2 + h) ^ (c31 & 7);
                bf16x8 kf = *(const bf16x8*)&Kl[buf][(s * 32 + c31) * 64 + pos * 8];
                st[s] = __builtin_amdgcn_mfma_f32_32x32x16_bf16(
                    kf, *(const bf16x8*)&qfrag[ks][0], st[s], 0, 0, 0);
            }
        }

        // ---- mask tail keys >= vl ----
        if (k0 + 64 > vl) {
#pragma unroll
            for (int s = 0; s < 2; ++s) {
                const int base = k0 + s * 32 + 4 * h;
#pragma unroll
                for (int r = 0; r < 16; ++r) {
                    const int key = base + (r & 3) + 8 * (r >> 2);
                    if (key >= vl) st[s][r] = -1e30f;
                }
            }
        }

        // ---- online softmax (log2 domain), q column = c31 ----
        float tm = st[0][0];
#pragma unroll
        for (int s = 0; s < 2; ++s)
#pragma unroll
            for (int r = 0; r < 16; ++r) tm = fmaxf(tm, st[s][r]);
        tm = fmaxf(tm, __shfl_xor(tm, 32));
        const float mnew = fmaxf(mrun, tm);
        const float corr = exp2f(mrun - mnew);
        mrun = mnew;
        float rs = 0.f;
#pragma unroll
        for (int s = 0; s < 2; ++s)
#pragma unroll
            for (int r = 0; r < 16; ++r) {
                const float p = exp2f(st[s][r] - mnew);
                st[s][r] = p;
                rs += p;
            }
        rs += __shfl_xor(rs, 32);
        lrun = lrun * corr + rs;
#pragma unroll
        for (int dt = 0; dt < 2; ++dt)
#pragma unroll
            for (int r = 0; r < 16; ++r) oacc[dt][r] *= corr;

        // ---- pack P to bf16 pairs: pk[s][m] = keys (8*(m>>1)+2*(m&1)+4h, +1) ----
        unsigned pk[2][8];
#pragma unroll
        for (int s = 0; s < 2; ++s)
#pragma unroll
            for (int m = 0; m < 8; ++m)
                pk[s][m] = pk_bf16(st[s][2 * m], st[s][2 * m + 1]);

        // ---- O^T += V^T * P^T : 4 k-steps x 2 dim-tiles ----
#pragma unroll
        for (int kq = 0; kq < 4; ++kq) {
            const int s = kq >> 1, A4 = (kq & 1) * 4;
            unsigned p0 = pk[s][A4], p1 = pk[s][A4+1], p2 = pk[s][A4+2], p3 = pk[s][A4+3];
            unsigned xp0 = __shfl_xor((int)p0, 32);
            unsigned xp1 = __shfl_xor((int)p1, 32);
            unsigned xp2 = __shfl_xor((int)p2, 32);
            unsigned xp3 = __shfl_xor((int)p3, 32);
            unsigned pf[4];
            pf[0] = h ? xp2 : p0;
            pf[1] = h ? xp3 : p1;
            pf[2] = h ? p2  : xp0;
            pf[3] = h ? p3  : xp1;
            const bf16x8 pfr = *(const bf16x8*)&pf[0];
#pragma unroll
            for (int dt = 0; dt < 2; ++dt) {
                const int pos = (kq * 2 + h) ^ (c31 & 7);
                bf16x8 vf = *(const bf16x8*)&Vt[buf][(dt * 32 + c31) * 64 + pos * 8];
                oacc[dt] = __builtin_amdgcn_mfma_f32_32x32x16_bf16(vf, pfr, oacc[dt], 0, 0, 0);
            }
        }
    }

    // ---- epilogue: normalize and store O[q][dim] ----
    const float inv = 1.f / lrun;
    float* op = O + ((size_t)(b * LQ_ + q0 + c31)) * D_;
#pragma unroll
    for (int dt = 0; dt < 2; ++dt)
#pragma unroll
        for (int g = 0; g < 4; ++g) {
            f32x4 v;
#pragma unroll
            for (int j = 0; j < 4; ++j) v[j] = oacc[dt][4 * g + j] * inv;
            *(f32x4*)(op + dt * 32 + 8 * g + 4 * h) = v;
        }
}

extern "C" void kernel_launch(void* const* d_in, const int* in_sizes, int n_in,
                              void* d_out, int out_size, void* d_ws, size_t ws_size,
                              hipStream_t stream) {
    const float* Q    = (const float*)d_in[0];
    const float* K    = (const float*)d_in[1];
    const float* V    = (const float*)d_in[2];
    const int*   vlen = (const int*)d_in[3];
    float*       O    = (float*)d_out;

    dim3 grid(LQ_ / 64, B_);
    dim3 block(128);
    fa_mfma3_kernel<<<grid, block, 0, stream>>>(Q, K, V, vlen, O);
}